// Round 5
// baseline (227.045 us; speedup 1.0000x reference)
//
#include <hip/hip_runtime.h>

#define SEQ   4096
#define HH    4
#define SCALE 0.125f
// exp2-folded constants: p = exp2(s*SC2 + a2), SC2 = SCALE*log2(e).
// SC2 is folded into Q at projection time (wq,bq pre-scaled), so the exp
// argument is just (accumulator + bias), and the bias rides in the MFMA C-init.
#define SC2   0.18033688011112042f
#define C16   -23.083120654223414f   /* -16*log2(e) */

typedef __bf16 bf16x8 __attribute__((ext_vector_type(8)));
typedef __bf16 bf16x4 __attribute__((ext_vector_type(4)));
typedef float  f32x4  __attribute__((ext_vector_type(4)));

// ---- ws layout (float offsets) ----
// Q frag-packed: [bh][tile16][frag2][512] (Q pre-scaled by SC2);
// K frag-packed with PERMUTED rows: [bh][jc32][tile2][frag2][512],
//   tile row m <-> j = (m>>2)*8 + t*4 + (m&3) so S^T = mfma(K,Q) lands
//   directly in the PV B-fragment layout (no cross-lane redistribution).
// V: [bh][jc32][nd4][512].
constexpr size_t OFF_W16  = 0;         // 4x65536 bf16 weights (wq slab pre-scaled by SC2)
constexpr size_t OFF_A    = 131072;    // [bh*S+j] a2_j = C16 - log2(Z_j)
constexpr size_t OFF_AO   = 294912;    // [8192][256] fp32 attn out (atomic)
constexpr size_t OFF_X16  = 9732096;   // 6291456 bf16 (x cast)
constexpr size_t OFF_Q16  = 12877824;  // packed Q,K,V bf16 regions
constexpr size_t K16OFF   = 2097152;
constexpr size_t V16OFF   = 4194304;
constexpr size_t OFF_PZ   = 16023552;  // [16][32768] colstats partials

__device__ __forceinline__ f32x4 mf(bf16x8 a, bf16x8 b, f32x4 c) {
    return __builtin_amdgcn_mfma_f32_16x16x32_bf16(a, b, c, 0, 0, 0);
}

__device__ __forceinline__ void gload16(const __bf16* g, __bf16* l) {
    __builtin_amdgcn_global_load_lds(
        (const __attribute__((address_space(1))) unsigned int*)g,
        (__attribute__((address_space(3))) unsigned int*)l, 16, 0, 0);
}

__device__ __forceinline__ float ex2(float x) {
    return __builtin_amdgcn_exp2f(x);
}

// ---- prep: cast x, cast weights (wq pre-scaled by SC2), zero AO ----
__global__ void k_prep(const float* __restrict__ x,
                       const float* __restrict__ wq, const float* __restrict__ wk,
                       const float* __restrict__ wv, const float* __restrict__ wo,
                       float* __restrict__ ws) {
    int bx = blockIdx.x, t = threadIdx.x;
    if (bx < 6144) {
        size_t i4 = ((size_t)bx * 256 + t) * 4;
        float4 v = *(const float4*)(x + i4);
        bf16x4 o = {(__bf16)v.x, (__bf16)v.y, (__bf16)v.z, (__bf16)v.w};
        *(bf16x4*)((__bf16*)(ws + OFF_X16) + i4) = o;
    } else if (bx < 6400) {
        int q = bx - 6144;
        int y = q >> 6;
        const float* src = (y == 0) ? wq : (y == 1) ? wk : (y == 2) ? wv : wo;
        float sc = (y == 0) ? SC2 : 1.0f;
        size_t i4 = ((size_t)(q & 63) * 256 + t) * 4;
        float4 v = *(const float4*)(src + i4);
        bf16x4 o = {(__bf16)(v.x * sc), (__bf16)(v.y * sc),
                    (__bf16)(v.z * sc), (__bf16)(v.w * sc)};
        *(bf16x4*)((__bf16*)(ws + OFF_W16) + (size_t)y * 65536 + i4) = o;
    } else {
        size_t i4 = ((size_t)(bx - 6400) * 256 + t) * 4;
        *(float4*)(ws + OFF_AO + i4) = make_float4(0.f, 0.f, 0.f, 0.f);
    }
}

// ---- QKV projection; grid (128, 3, 2): z splits the 256-col output ----
__global__ __launch_bounds__(256) void k_qkv_mfma(const float* __restrict__ bq,
                                                  const float* __restrict__ bk,
                                                  const float* __restrict__ bv,
                                                  float* __restrict__ ws) {
    int t = threadIdx.x, lane = t & 63, w = t >> 6;
    int yw = blockIdx.y;
    int ntb = blockIdx.z * 8;
    int row0 = blockIdx.x * 64 + w * 16;
    int mrow = lane & 15, quad = lane >> 4;
    const __bf16* X16 = (const __bf16*)(ws + OFF_X16);
    const __bf16* W16 = (const __bf16*)(ws + OFF_W16) + (size_t)yw * 65536;
    const float* bias = (yw == 0) ? bq : (yw == 1) ? bk : bv;
    __bf16* Qb = (__bf16*)(ws + OFF_Q16);
    f32x4 acc[8];
#pragma unroll
    for (int n = 0; n < 8; n++) acc[n] = {0.f, 0.f, 0.f, 0.f};
    const __bf16* ap = X16 + (size_t)(row0 + mrow) * 768 + yw * 256 + quad * 8;
    const __bf16* bp = W16 + (size_t)ntb * 4096 + (size_t)mrow * 256 + quad * 8;
    for (int kc = 0; kc < 256; kc += 32) {
        bf16x8 a = *(const bf16x8*)(ap + kc);
#pragma unroll
        for (int nt = 0; nt < 8; nt++) {
            bf16x8 b = *(const bf16x8*)(bp + (size_t)nt * 4096 + kc);
            acc[nt] = mf(a, b, acc[nt]);
        }
    }
#pragma unroll
    for (int nt = 0; nt < 8; nt++) {
        int n = (ntb + nt) * 16 + mrow;
        float bb = bias[n];
        if (yw == 0) bb *= SC2;
        int h = n >> 6, d = n & 63;
#pragma unroll
        for (int r = 0; r < 4; r++) {
            int sg = row0 + quad * 4 + r;
            int b_ = sg >> 12, s = sg & 4095;
            int bh = b_ * HH + h;
            float val = acc[nt][r] + bb;
            if (yw == 0) {
                int tile = s >> 4, m = s & 15, frag = d >> 5, q2 = (d >> 3) & 3, e = d & 7;
                size_t idx = (((size_t)bh * 256 + tile) * 2 + frag) * 512 +
                             (size_t)(q2 * 16 + m) * 8 + e;
                Qb[idx] = (__bf16)val;
            } else if (yw == 1) {
                int jc = s >> 5, jj = s & 31;
                int tl = (jj >> 2) & 1, m = ((jj >> 3) << 2) | (jj & 3);
                int frag = d >> 5, q2 = (d >> 3) & 3, e = d & 7;
                size_t idx = (((size_t)bh * 128 + jc) * 4 + tl * 2 + frag) * 512 +
                             (size_t)(q2 * 16 + m) * 8 + e;
                Qb[K16OFF + idx] = (__bf16)val;
            } else {
                int jc = s >> 5, qk = (s >> 3) & 3, e = s & 7;
                int nd = d >> 4, nl = d & 15;
                size_t idx = (((size_t)bh * 128 + jc) * 4 + nd) * 512 +
                             (size_t)(qk * 16 + nl) * 8 + e;
                Qb[V16OFF + idx] = (__bf16)val;
            }
        }
    }
}

// ---- pass 1: Z_j partials; 64 j/wave (8 K frags), 256 i/block ----
// grid (16 jb, 16 iy, 8 bh) = 2048 blocks; Q staged 64-i chunks dbuf'd.
__global__ __launch_bounds__(256) void k_colstats(float* __restrict__ ws) {
    __shared__ __bf16 qbuf[2][4096];
    int t = threadIdx.x, lane = t & 63, w = t >> 6;
    int jb = blockIdx.x, iy = blockIdx.y, bh = blockIdx.z;
    int jc0 = jb * 8 + w * 2;          // two 32-j chunks per wave
    const __bf16* Qp = (const __bf16*)(ws + OFF_Q16);
    const __bf16* Kp = Qp + K16OFF;
    const __bf16* kb = Kp + ((size_t)(bh * 128 + jc0) * 4) * 512 + lane * 8;
    bf16x8 kA0 = *(const bf16x8*)(kb);
    bf16x8 kA1 = *(const bf16x8*)(kb + 512);
    bf16x8 kB0 = *(const bf16x8*)(kb + 1024);
    bf16x8 kB1 = *(const bf16x8*)(kb + 1536);
    bf16x8 kC0 = *(const bf16x8*)(kb + 2048);
    bf16x8 kC1 = *(const bf16x8*)(kb + 2560);
    bf16x8 kD0 = *(const bf16x8*)(kb + 3072);
    bf16x8 kD1 = *(const bf16x8*)(kb + 3584);
    const __bf16* q0 = Qp + ((size_t)(bh * 256 + iy * 16) * 2) * 512 +
                       w * 1024 + lane * 8;
    gload16(q0, qbuf[0] + w * 1024);
    gload16(q0 + 512, qbuf[0] + w * 1024 + 512);
    __syncthreads();
    const f32x4 cin = {C16, C16, C16, C16};
    float z0 = 0.f, z1 = 0.f, z2 = 0.f, z3 = 0.f;
    for (int ic = 0; ic < 4; ic++) {
        const __bf16* cur = qbuf[ic & 1];
        if (ic < 3) {
            const __bf16* qn = Qp + ((size_t)(bh * 256 + iy * 16 + (ic + 1) * 4) * 2) * 512 +
                               w * 1024 + lane * 8;
            gload16(qn, qbuf[(ic + 1) & 1] + w * 1024);
            gload16(qn + 512, qbuf[(ic + 1) & 1] + w * 1024 + 512);
        }
#pragma unroll
        for (int it = 0; it < 4; it++) {
            bf16x8 a0 = *(const bf16x8*)(cur + it * 1024 + lane * 8);
            bf16x8 a1 = *(const bf16x8*)(cur + it * 1024 + 512 + lane * 8);
            f32x4 cA = mf(a0, kA0, cin); cA = mf(a1, kA1, cA);
            f32x4 cB = mf(a0, kB0, cin); cB = mf(a1, kB1, cB);
            f32x4 cC = mf(a0, kC0, cin); cC = mf(a1, kC1, cC);
            f32x4 cD = mf(a0, kD0, cin); cD = mf(a1, kD1, cD);
#pragma unroll
            for (int r = 0; r < 4; r++) {
                z0 += ex2(cA[r]);
                z1 += ex2(cB[r]);
                z2 += ex2(cC[r]);
                z3 += ex2(cD[r]);
            }
        }
        __syncthreads();
    }
    z0 += __shfl_xor(z0, 16, 64);
    z0 += __shfl_xor(z0, 32, 64);
    z1 += __shfl_xor(z1, 16, 64);
    z1 += __shfl_xor(z1, 32, 64);
    z2 += __shfl_xor(z2, 16, 64);
    z2 += __shfl_xor(z2, 32, 64);
    z3 += __shfl_xor(z3, 16, 64);
    z3 += __shfl_xor(z3, 32, 64);
    if (lane < 16) {
        // col m of tile t in chunk c -> j = (jc0+c)*32 + (m>>2)*8 + t*4 + (m&3)
        size_t o = OFF_PZ + (size_t)iy * 32768 + (size_t)bh * SEQ +
                   jc0 * 32 + ((lane >> 2) << 3) + (lane & 3);
        ws[o] = z0;
        ws[o + 4] = z1;
        ws[o + 32] = z2;
        ws[o + 36] = z3;
    }
}

// ---- pass 1b: a2_j = C16 - log2(sum of partials) ----
__global__ void k_afin(float* __restrict__ ws) {
    int idx = blockIdx.x * 256 + threadIdx.x;
    const float* pz = ws + OFF_PZ;
    float Z = 0.f;
#pragma unroll
    for (int y = 0; y < 16; y++) Z += pz[(size_t)y * 32768 + idx];
    ws[OFF_A + idx] = C16 - __log2f(Z);
}

// ---- pass 2: 32 i/wave, 512 j/block (16 jt); K LDS-staged dbuf,
// V + a2 direct global->reg (V issued at loop top, consumed post-exp).
// grid (32,8,8) = 2048 blocks -> 8/CU. ----
__global__ __launch_bounds__(256) void k_attnpv(float* __restrict__ ws) {
    __shared__ __align__(16) char pool[17408];
    __bf16* ldsK = (__bf16*)pool;            // [2][2048] K double-buffer
    int t = threadIdx.x, lane = t & 63, w = t >> 6;
    int jy = blockIdx.y, bh = blockIdx.z;    // jy: 512-j slab
    int itp = blockIdx.x * 4 + w;            // 0..127
    int it0 = itp * 2;                       // two 16-row Q tiles
    int mrow = lane & 15, quad = lane >> 4;
    const __bf16* Qp = (const __bf16*)(ws + OFF_Q16);
    const __bf16* Kp = Qp + K16OFF;
    const __bf16* Vp = Qp + V16OFF;
    const float* Ag = ws + OFF_A + (size_t)bh * SEQ + jy * 512 + quad * 8;

    const __bf16* qb = Qp + ((size_t)(bh * 256 + it0) * 2) * 512 + lane * 8;
    bf16x8 aq00 = *(const bf16x8*)(qb);
    bf16x8 aq01 = *(const bf16x8*)(qb + 512);
    bf16x8 aq10 = *(const bf16x8*)(qb + 1024);
    bf16x8 aq11 = *(const bf16x8*)(qb + 1536);

    f32x4 oT0[4], oT1[4];
#pragma unroll
    for (int nd = 0; nd < 4; nd++) {
        oT0[nd] = {0.f, 0.f, 0.f, 0.f};
        oT1[nd] = {0.f, 0.f, 0.f, 0.f};
    }
    int c0g = jy * 16;                       // first 32-j chunk of this slab
    const __bf16* kg = Kp + ((size_t)(bh * 128 + c0g) * 4) * 512 + w * 512 + lane * 8;
    gload16(kg, ldsK + w * 512);
    kg += 2048;
    const __bf16* vgb = Vp + ((size_t)(bh * 128 + c0g) * 4) * 512 + lane * 8;
    f32x4 aL = *(const f32x4*)(Ag);
    f32x4 aH = *(const f32x4*)(Ag + 4);
    __syncthreads();

    for (int jt = 0; jt < 16; jt++) {
        const __bf16* curK = ldsK + (jt & 1) * 2048;
        // V for this jt: direct global->reg, ~full S/exp phase of slack
        bf16x8 bv0 = *(const bf16x8*)(vgb);
        bf16x8 bv1 = *(const bf16x8*)(vgb + 512);
        bf16x8 bv2 = *(const bf16x8*)(vgb + 1024);
        bf16x8 bv3 = *(const bf16x8*)(vgb + 1536);
        vgb += 2048;
        f32x4 aLn = aL, aHn = aH;
        if (jt < 15) {
            gload16(kg, ldsK + ((jt + 1) & 1) * 2048 + w * 512);
            kg += 2048;
            aLn = *(const f32x4*)(Ag + (jt + 1) * 32);
            aHn = *(const f32x4*)(Ag + (jt + 1) * 32 + 4);
        }
        bf16x8 ck0 = *(const bf16x8*)(curK + lane * 8);
        bf16x8 ck1 = *(const bf16x8*)(curK + 512 + lane * 8);
        bf16x8 ck2 = *(const bf16x8*)(curK + 1024 + lane * 8);
        bf16x8 ck3 = *(const bf16x8*)(curK + 1536 + lane * 8);
        // S^T with bias folded into C-init: c = s*SC2 + a2  (Q pre-scaled)
        f32x4 c00 = mf(ck0, aq00, aL); c00 = mf(ck1, aq01, c00);
        f32x4 c01 = mf(ck2, aq00, aH); c01 = mf(ck3, aq01, c01);
        f32x4 c10 = mf(ck0, aq10, aL); c10 = mf(ck1, aq11, c10);
        f32x4 c11 = mf(ck2, aq10, aH); c11 = mf(ck3, aq11, c11);
        bf16x8 pb0, pb1;
#pragma unroll
        for (int r = 0; r < 4; r++) {
            pb0[r]     = (__bf16)ex2(c00[r]);
            pb0[4 + r] = (__bf16)ex2(c01[r]);
            pb1[r]     = (__bf16)ex2(c10[r]);
            pb1[4 + r] = (__bf16)ex2(c11[r]);
        }
        oT0[0] = mf(bv0, pb0, oT0[0]);
        oT1[0] = mf(bv0, pb1, oT1[0]);
        oT0[1] = mf(bv1, pb0, oT0[1]);
        oT1[1] = mf(bv1, pb1, oT1[1]);
        oT0[2] = mf(bv2, pb0, oT0[2]);
        oT1[2] = mf(bv2, pb1, oT1[2]);
        oT0[3] = mf(bv3, pb0, oT0[3]);
        oT1[3] = mf(bv3, pb1, oT1[3]);
        aL = aLn; aH = aHn;
        __syncthreads();
    }

    // epilogue: wave-local LDS transpose (pool is dead), coalesced atomics
    float* sO = (float*)pool + (size_t)w * 1040;   // 16 x 65 floats per wave
    int b = bh >> 2, h = bh & 3;
    float* AO = ws + OFF_AO;
    int i0 = it0 * 16;
#pragma unroll
    for (int nd = 0; nd < 4; nd++)
#pragma unroll
        for (int r = 0; r < 4; r++)
            sO[mrow * 65 + nd * 16 + quad * 4 + r] = oT0[nd][r];
#pragma unroll
    for (int c = 0; c < 16; c++)
        atomicAdd(&AO[((size_t)(b * SEQ + i0 + c)) * 256 + h * 64 + lane],
                  sO[c * 65 + lane]);
#pragma unroll
    for (int nd = 0; nd < 4; nd++)
#pragma unroll
        for (int r = 0; r < 4; r++)
            sO[mrow * 65 + nd * 16 + quad * 4 + r] = oT1[nd][r];
#pragma unroll
    for (int c = 0; c < 16; c++)
        atomicAdd(&AO[((size_t)(b * SEQ + i0 + 16 + c)) * 256 + h * 64 + lane],
                  sO[c * 65 + lane]);
}

// ---- output projection; grid (128, 4): y splits cols -> 512 blocks ----
__global__ __launch_bounds__(256) void k_outproj_mfma(const float* __restrict__ bo,
                                                      float* __restrict__ ws,
                                                      float* __restrict__ out) {
    int t = threadIdx.x, lane = t & 63, w = t >> 6;
    int row0 = blockIdx.x * 64 + w * 16;
    int ntb = blockIdx.y * 4;
    int mrow = lane & 15, quad = lane >> 4;
    const float* AO = ws + OFF_AO;
    const __bf16* W16 = (const __bf16*)(ws + OFF_W16) + (size_t)3 * 65536;
    f32x4 acc[4];
#pragma unroll
    for (int n = 0; n < 4; n++) acc[n] = {0.f, 0.f, 0.f, 0.f};
    const float* ap = AO + (size_t)(row0 + mrow) * 256 + quad * 8;
    const __bf16* bp = W16 + (size_t)ntb * 4096 + (size_t)mrow * 256 + quad * 8;
    for (int kc = 0; kc < 256; kc += 32) {
        float4 u = *(const float4*)(ap + kc);
        float4 v = *(const float4*)(ap + kc + 4);
        bf16x8 a = {(__bf16)u.x, (__bf16)u.y, (__bf16)u.z, (__bf16)u.w,
                    (__bf16)v.x, (__bf16)v.y, (__bf16)v.z, (__bf16)v.w};
#pragma unroll
        for (int nt = 0; nt < 4; nt++) {
            bf16x8 b = *(const bf16x8*)(bp + (size_t)nt * 4096 + kc);
            acc[nt] = mf(a, b, acc[nt]);
        }
    }
#pragma unroll
    for (int nt = 0; nt < 4; nt++) {
        int n = (ntb + nt) * 16 + mrow;
        float bb = bo[n];
#pragma unroll
        for (int r = 0; r < 4; r++) {
            int sg = row0 + quad * 4 + r;
            out[(size_t)sg * 256 + n] = acc[nt][r] + bb;
        }
    }
}

extern "C" void kernel_launch(void* const* d_in, const int* in_sizes, int n_in,
                              void* d_out, int out_size, void* d_ws, size_t ws_size,
                              hipStream_t stream) {
    const float* x  = (const float*)d_in[0];
    const float* wq = (const float*)d_in[1];
    const float* bq = (const float*)d_in[2];
    const float* wk = (const float*)d_in[3];
    const float* bk = (const float*)d_in[4];
    const float* wv = (const float*)d_in[5];
    const float* bv = (const float*)d_in[6];
    const float* wo = (const float*)d_in[7];
    const float* bo = (const float*)d_in[8];
    float* ws = (float*)d_ws;
    float* out = (float*)d_out;

    k_prep<<<8448, 256, 0, stream>>>(x, wq, wk, wv, wo, ws);
    k_qkv_mfma<<<dim3(128, 3, 2), 256, 0, stream>>>(bq, bk, bv, ws);
    k_colstats<<<dim3(16, 16, 8), 256, 0, stream>>>(ws);
    k_afin<<<128, 256, 0, stream>>>(ws);
    k_attnpv<<<dim3(32, 8, 8), 256, 0, stream>>>(ws);
    k_outproj_mfma<<<dim3(128, 4), 256, 0, stream>>>(bo, ws, out);
}

// Round 7
// 220.345 us; speedup vs baseline: 1.0304x; 1.0304x over previous
//
#include <hip/hip_runtime.h>

#define SEQ   4096
#define HH    4
#define SCALE 0.125f
// exp2-folded constants: p = exp2(s*SC2 + a2), SC2 = SCALE*log2(e).
// SC2 is folded into Q at projection time (wq,bq pre-scaled); a2_j rides in
// the MFMA C-initializer. NOTE: softmax normalizes over i (axis=1), so the
// stats pass computes COLUMN sums Z_j = sum_i exp2(s'_ij + C16).
#define SC2   0.18033688011112042f
#define C16   -23.083120654223414f   /* -16*log2(e) */

typedef __bf16 bf16x8 __attribute__((ext_vector_type(8)));
typedef __bf16 bf16x4 __attribute__((ext_vector_type(4)));
typedef float  f32x4  __attribute__((ext_vector_type(4)));

// ---- ws layout (float offsets) ----
// Q frag-packed: [bh][tile16][frag2][512] (Q pre-scaled by SC2);
// K frag-packed with PERMUTED rows: [bh][jc32][tile2][frag2][512],
//   tile row m <-> j = (m>>2)*8 + t*4 + (m&3) so S^T = mfma(K,Q) lands
//   directly in the PV B-fragment layout (no cross-lane redistribution).
// V: [bh][jc32][nd4][512].
constexpr size_t OFF_W16  = 0;         // 4x65536 bf16 weights (wq slab pre-scaled by SC2)
constexpr size_t OFF_A    = 131072;    // [bh*S+j] a2_j = C16 - log2(Z_j)
constexpr size_t OFF_AO   = 294912;    // [8192][256] fp32 attn out (atomic)
constexpr size_t OFF_X16  = 9732096;   // 6291456 bf16 (x cast)
constexpr size_t OFF_Q16  = 12877824;  // packed Q,K,V bf16 regions
constexpr size_t K16OFF   = 2097152;
constexpr size_t V16OFF   = 4194304;
constexpr size_t OFF_PZ   = 16023552;  // [16][32768] colstats partials

__device__ __forceinline__ f32x4 mf(bf16x8 a, bf16x8 b, f32x4 c) {
    return __builtin_amdgcn_mfma_f32_16x16x32_bf16(a, b, c, 0, 0, 0);
}

__device__ __forceinline__ void gload16(const __bf16* g, __bf16* l) {
    __builtin_amdgcn_global_load_lds(
        (const __attribute__((address_space(1))) unsigned int*)g,
        (__attribute__((address_space(3))) unsigned int*)l, 16, 0, 0);
}

__device__ __forceinline__ float ex2(float x) {
    return __builtin_amdgcn_exp2f(x);
}

// ---- prep: cast x, cast weights (wq pre-scaled by SC2), zero AO ----
__global__ void k_prep(const float* __restrict__ x,
                       const float* __restrict__ wq, const float* __restrict__ wk,
                       const float* __restrict__ wv, const float* __restrict__ wo,
                       float* __restrict__ ws) {
    int bx = blockIdx.x, t = threadIdx.x;
    if (bx < 6144) {
        size_t i4 = ((size_t)bx * 256 + t) * 4;
        float4 v = *(const float4*)(x + i4);
        bf16x4 o = {(__bf16)v.x, (__bf16)v.y, (__bf16)v.z, (__bf16)v.w};
        *(bf16x4*)((__bf16*)(ws + OFF_X16) + i4) = o;
    } else if (bx < 6400) {
        int q = bx - 6144;
        int y = q >> 6;
        const float* src = (y == 0) ? wq : (y == 1) ? wk : (y == 2) ? wv : wo;
        float sc = (y == 0) ? SC2 : 1.0f;
        size_t i4 = ((size_t)(q & 63) * 256 + t) * 4;
        float4 v = *(const float4*)(src + i4);
        bf16x4 o = {(__bf16)(v.x * sc), (__bf16)(v.y * sc),
                    (__bf16)(v.z * sc), (__bf16)(v.w * sc)};
        *(bf16x4*)((__bf16*)(ws + OFF_W16) + (size_t)y * 65536 + i4) = o;
    } else {
        size_t i4 = ((size_t)(bx - 6400) * 256 + t) * 4;
        *(float4*)(ws + OFF_AO + i4) = make_float4(0.f, 0.f, 0.f, 0.f);
    }
}

// ---- QKV projection; grid (128, 3, 2): z splits the 256-col output ----
__global__ __launch_bounds__(256) void k_qkv_mfma(const float* __restrict__ bq,
                                                  const float* __restrict__ bk,
                                                  const float* __restrict__ bv,
                                                  float* __restrict__ ws) {
    int t = threadIdx.x, lane = t & 63, w = t >> 6;
    int yw = blockIdx.y;
    int ntb = blockIdx.z * 8;
    int row0 = blockIdx.x * 64 + w * 16;
    int mrow = lane & 15, quad = lane >> 4;
    const __bf16* X16 = (const __bf16*)(ws + OFF_X16);
    const __bf16* W16 = (const __bf16*)(ws + OFF_W16) + (size_t)yw * 65536;
    const float* bias = (yw == 0) ? bq : (yw == 1) ? bk : bv;
    __bf16* Qb = (__bf16*)(ws + OFF_Q16);
    f32x4 acc[8];
#pragma unroll
    for (int n = 0; n < 8; n++) acc[n] = {0.f, 0.f, 0.f, 0.f};
    const __bf16* ap = X16 + (size_t)(row0 + mrow) * 768 + yw * 256 + quad * 8;
    const __bf16* bp = W16 + (size_t)ntb * 4096 + (size_t)mrow * 256 + quad * 8;
    for (int kc = 0; kc < 256; kc += 32) {
        bf16x8 a = *(const bf16x8*)(ap + kc);
#pragma unroll
        for (int nt = 0; nt < 8; nt++) {
            bf16x8 b = *(const bf16x8*)(bp + (size_t)nt * 4096 + kc);
            acc[nt] = mf(a, b, acc[nt]);
        }
    }
#pragma unroll
    for (int nt = 0; nt < 8; nt++) {
        int n = (ntb + nt) * 16 + mrow;
        float bb = bias[n];
        if (yw == 0) bb *= SC2;
        int h = n >> 6, d = n & 63;
#pragma unroll
        for (int r = 0; r < 4; r++) {
            int sg = row0 + quad * 4 + r;
            int b_ = sg >> 12, s = sg & 4095;
            int bh = b_ * HH + h;
            float val = acc[nt][r] + bb;
            if (yw == 0) {
                int tile = s >> 4, m = s & 15, frag = d >> 5, q2 = (d >> 3) & 3, e = d & 7;
                size_t idx = (((size_t)bh * 256 + tile) * 2 + frag) * 512 +
                             (size_t)(q2 * 16 + m) * 8 + e;
                Qb[idx] = (__bf16)val;
            } else if (yw == 1) {
                int jc = s >> 5, jj = s & 31;
                int tl = (jj >> 2) & 1, m = ((jj >> 3) << 2) | (jj & 3);
                int frag = d >> 5, q2 = (d >> 3) & 3, e = d & 7;
                size_t idx = (((size_t)bh * 128 + jc) * 4 + tl * 2 + frag) * 512 +
                             (size_t)(q2 * 16 + m) * 8 + e;
                Qb[K16OFF + idx] = (__bf16)val;
            } else {
                int jc = s >> 5, qk = (s >> 3) & 3, e = s & 7;
                int nd = d >> 4, nl = d & 15;
                size_t idx = (((size_t)bh * 128 + jc) * 4 + nd) * 512 +
                             (size_t)(qk * 16 + nl) * 8 + e;
                Qb[V16OFF + idx] = (__bf16)val;
            }
        }
    }
}

// ---- pass 1: Z_j partials; 64 j/wave (8 K frags), 256 i/block ----
// grid (16 jb, 16 iy, 8 bh) = 2048 blocks; Q staged 64-i chunks dbuf'd.
__global__ __launch_bounds__(256) void k_colstats(float* __restrict__ ws) {
    __shared__ __bf16 qbuf[2][4096];
    int t = threadIdx.x, lane = t & 63, w = t >> 6;
    int jb = blockIdx.x, iy = blockIdx.y, bh = blockIdx.z;
    int jc0 = jb * 8 + w * 2;          // two 32-j chunks per wave
    const __bf16* Qp = (const __bf16*)(ws + OFF_Q16);
    const __bf16* Kp = Qp + K16OFF;
    const __bf16* kb = Kp + ((size_t)(bh * 128 + jc0) * 4) * 512 + lane * 8;
    bf16x8 kA0 = *(const bf16x8*)(kb);
    bf16x8 kA1 = *(const bf16x8*)(kb + 512);
    bf16x8 kB0 = *(const bf16x8*)(kb + 1024);
    bf16x8 kB1 = *(const bf16x8*)(kb + 1536);
    bf16x8 kC0 = *(const bf16x8*)(kb + 2048);
    bf16x8 kC1 = *(const bf16x8*)(kb + 2560);
    bf16x8 kD0 = *(const bf16x8*)(kb + 3072);
    bf16x8 kD1 = *(const bf16x8*)(kb + 3584);
    const __bf16* q0 = Qp + ((size_t)(bh * 256 + iy * 16) * 2) * 512 +
                       w * 1024 + lane * 8;
    gload16(q0, qbuf[0] + w * 1024);
    gload16(q0 + 512, qbuf[0] + w * 1024 + 512);
    __syncthreads();
    const f32x4 cin = {C16, C16, C16, C16};
    float z0 = 0.f, z1 = 0.f, z2 = 0.f, z3 = 0.f;
    for (int ic = 0; ic < 4; ic++) {
        const __bf16* cur = qbuf[ic & 1];
        if (ic < 3) {
            const __bf16* qn = Qp + ((size_t)(bh * 256 + iy * 16 + (ic + 1) * 4) * 2) * 512 +
                               w * 1024 + lane * 8;
            gload16(qn, qbuf[(ic + 1) & 1] + w * 1024);
            gload16(qn + 512, qbuf[(ic + 1) & 1] + w * 1024 + 512);
        }
#pragma unroll
        for (int it = 0; it < 4; it++) {
            bf16x8 a0 = *(const bf16x8*)(cur + it * 1024 + lane * 8);
            bf16x8 a1 = *(const bf16x8*)(cur + it * 1024 + 512 + lane * 8);
            f32x4 cA = mf(a0, kA0, cin); cA = mf(a1, kA1, cA);
            f32x4 cB = mf(a0, kB0, cin); cB = mf(a1, kB1, cB);
            f32x4 cC = mf(a0, kC0, cin); cC = mf(a1, kC1, cC);
            f32x4 cD = mf(a0, kD0, cin); cD = mf(a1, kD1, cD);
#pragma unroll
            for (int r = 0; r < 4; r++) {
                z0 += ex2(cA[r]);
                z1 += ex2(cB[r]);
                z2 += ex2(cC[r]);
                z3 += ex2(cD[r]);
            }
        }
        __syncthreads();
    }
    z0 += __shfl_xor(z0, 16, 64);
    z0 += __shfl_xor(z0, 32, 64);
    z1 += __shfl_xor(z1, 16, 64);
    z1 += __shfl_xor(z1, 32, 64);
    z2 += __shfl_xor(z2, 16, 64);
    z2 += __shfl_xor(z2, 32, 64);
    z3 += __shfl_xor(z3, 16, 64);
    z3 += __shfl_xor(z3, 32, 64);
    if (lane < 16) {
        // col m of tile t in chunk c -> j = (jc0+c)*32 + (m>>2)*8 + t*4 + (m&3)
        size_t o = OFF_PZ + (size_t)iy * 32768 + (size_t)bh * SEQ +
                   jc0 * 32 + ((lane >> 2) << 3) + (lane & 3);
        ws[o] = z0;
        ws[o + 4] = z1;
        ws[o + 32] = z2;
        ws[o + 36] = z3;
    }
}

// ---- pass 1b: a2_j = C16 - log2(sum of partials) ----
__global__ void k_afin(float* __restrict__ ws) {
    int idx = blockIdx.x * 256 + threadIdx.x;
    const float* pz = ws + OFF_PZ;
    float Z = 0.f;
#pragma unroll
    for (int y = 0; y < 16; y++) Z += pz[(size_t)y * 32768 + idx];
    ws[OFF_A + idx] = C16 - __log2f(Z);
}

// ---- pass 2: 32 i/wave, 512 j/block (16 jt); K AND V LDS-staged dbuf
// (full-iteration prefetch slack), a2 in MFMA C-init, a2 prefetched from
// global 1 iter ahead. grid (32,8,8) = 2048 blocks -> 8/CU. ----
__global__ __launch_bounds__(256) void k_attnpv(float* __restrict__ ws) {
    __shared__ __align__(16) char pool[17408];
    __bf16* ldsK = (__bf16*)pool;            // [2][2048]
    __bf16* ldsV = (__bf16*)(pool + 8192);   // [2][2048]
    int t = threadIdx.x, lane = t & 63, w = t >> 6;
    int jy = blockIdx.y, bh = blockIdx.z;    // jy: 512-j slab
    int itp = blockIdx.x * 4 + w;            // 0..127
    int it0 = itp * 2;                       // two 16-row Q tiles
    int mrow = lane & 15, quad = lane >> 4;
    const __bf16* Qp = (const __bf16*)(ws + OFF_Q16);
    const __bf16* Kp = Qp + K16OFF;
    const __bf16* Vp = Qp + V16OFF;
    const float* Ag = ws + OFF_A + (size_t)bh * SEQ + jy * 512 + quad * 8;

    const __bf16* qb = Qp + ((size_t)(bh * 256 + it0) * 2) * 512 + lane * 8;
    bf16x8 aq00 = *(const bf16x8*)(qb);
    bf16x8 aq01 = *(const bf16x8*)(qb + 512);
    bf16x8 aq10 = *(const bf16x8*)(qb + 1024);
    bf16x8 aq11 = *(const bf16x8*)(qb + 1536);

    f32x4 oT0[4], oT1[4];
#pragma unroll
    for (int nd = 0; nd < 4; nd++) {
        oT0[nd] = {0.f, 0.f, 0.f, 0.f};
        oT1[nd] = {0.f, 0.f, 0.f, 0.f};
    }
    int c0g = jy * 16;                       // first 32-j chunk of this slab
    const __bf16* kg = Kp + ((size_t)(bh * 128 + c0g) * 4) * 512 + w * 512 + lane * 8;
    const __bf16* vg = Vp + ((size_t)(bh * 128 + c0g) * 4) * 512 + w * 512 + lane * 8;
    gload16(kg, ldsK + w * 512);
    gload16(vg, ldsV + w * 512);
    kg += 2048; vg += 2048;
    f32x4 aL = *(const f32x4*)(Ag);
    f32x4 aH = *(const f32x4*)(Ag + 4);
    __syncthreads();

    for (int jt = 0; jt < 16; jt++) {
        const __bf16* curK = ldsK + (jt & 1) * 2048;
        const __bf16* curV = ldsV + (jt & 1) * 2048;
        f32x4 aLn = aL, aHn = aH;
        if (jt < 15) {
            gload16(kg, ldsK + ((jt + 1) & 1) * 2048 + w * 512);
            gload16(vg, ldsV + ((jt + 1) & 1) * 2048 + w * 512);
            kg += 2048; vg += 2048;
            aLn = *(const f32x4*)(Ag + (jt + 1) * 32);
            aHn = *(const f32x4*)(Ag + (jt + 1) * 32 + 4);
        }
        bf16x8 ck0 = *(const bf16x8*)(curK + lane * 8);
        bf16x8 ck1 = *(const bf16x8*)(curK + 512 + lane * 8);
        bf16x8 ck2 = *(const bf16x8*)(curK + 1024 + lane * 8);
        bf16x8 ck3 = *(const bf16x8*)(curK + 1536 + lane * 8);
        // S^T with bias folded into C-init: c = s*SC2 + a2  (Q pre-scaled)
        f32x4 c00 = mf(ck0, aq00, aL); c00 = mf(ck1, aq01, c00);
        f32x4 c01 = mf(ck2, aq00, aH); c01 = mf(ck3, aq01, c01);
        f32x4 c10 = mf(ck0, aq10, aL); c10 = mf(ck1, aq11, c10);
        f32x4 c11 = mf(ck2, aq10, aH); c11 = mf(ck3, aq11, c11);
        bf16x8 pb0, pb1;
#pragma unroll
        for (int r = 0; r < 4; r++) {
            pb0[r]     = (__bf16)ex2(c00[r]);
            pb0[4 + r] = (__bf16)ex2(c01[r]);
            pb1[r]     = (__bf16)ex2(c10[r]);
            pb1[4 + r] = (__bf16)ex2(c11[r]);
        }
#pragma unroll
        for (int nd = 0; nd < 4; nd++) {
            bf16x8 bv = *(const bf16x8*)(curV + nd * 512 + lane * 8);
            oT0[nd] = mf(bv, pb0, oT0[nd]);
            oT1[nd] = mf(bv, pb1, oT1[nd]);
        }
        aL = aLn; aH = aHn;
        __syncthreads();
    }

    // epilogue: wave-local LDS transpose (pool is dead), coalesced atomics
    float* sO = (float*)pool + (size_t)w * 1040;   // 16 x 65 floats per wave
    int b = bh >> 2, h = bh & 3;
    float* AO = ws + OFF_AO;
    int i0 = it0 * 16;
#pragma unroll
    for (int nd = 0; nd < 4; nd++)
#pragma unroll
        for (int r = 0; r < 4; r++)
            sO[mrow * 65 + nd * 16 + quad * 4 + r] = oT0[nd][r];
#pragma unroll
    for (int c = 0; c < 16; c++)
        atomicAdd(&AO[((size_t)(b * SEQ + i0 + c)) * 256 + h * 64 + lane],
                  sO[c * 65 + lane]);
#pragma unroll
    for (int nd = 0; nd < 4; nd++)
#pragma unroll
        for (int r = 0; r < 4; r++)
            sO[mrow * 65 + nd * 16 + quad * 4 + r] = oT1[nd][r];
#pragma unroll
    for (int c = 0; c < 16; c++)
        atomicAdd(&AO[((size_t)(b * SEQ + i0 + 16 + c)) * 256 + h * 64 + lane],
                  sO[c * 65 + lane]);
}

// ---- output projection; grid (128, 4): y splits cols -> 512 blocks ----
__global__ __launch_bounds__(256) void k_outproj_mfma(const float* __restrict__ bo,
                                                      float* __restrict__ ws,
                                                      float* __restrict__ out) {
    int t = threadIdx.x, lane = t & 63, w = t >> 6;
    int row0 = blockIdx.x * 64 + w * 16;
    int ntb = blockIdx.y * 4;
    int mrow = lane & 15, quad = lane >> 4;
    const float* AO = ws + OFF_AO;
    const __bf16* W16 = (const __bf16*)(ws + OFF_W16) + (size_t)3 * 65536;
    f32x4 acc[4];
#pragma unroll
    for (int n = 0; n < 4; n++) acc[n] = {0.f, 0.f, 0.f, 0.f};
    const float* ap = AO + (size_t)(row0 + mrow) * 256 + quad * 8;
    const __bf16* bp = W16 + (size_t)ntb * 4096 + (size_t)mrow * 256 + quad * 8;
    for (int kc = 0; kc < 256; kc += 32) {
        float4 u = *(const float4*)(ap + kc);
        float4 v = *(const float4*)(ap + kc + 4);
        bf16x8 a = {(__bf16)u.x, (__bf16)u.y, (__bf16)u.z, (__bf16)u.w,
                    (__bf16)v.x, (__bf16)v.y, (__bf16)v.z, (__bf16)v.w};
#pragma unroll
        for (int nt = 0; nt < 4; nt++) {
            bf16x8 b = *(const bf16x8*)(bp + (size_t)nt * 4096 + kc);
            acc[nt] = mf(a, b, acc[nt]);
        }
    }
#pragma unroll
    for (int nt = 0; nt < 4; nt++) {
        int n = (ntb + nt) * 16 + mrow;
        float bb = bo[n];
#pragma unroll
        for (int r = 0; r < 4; r++) {
            int sg = row0 + quad * 4 + r;
            out[(size_t)sg * 256 + n] = acc[nt][r] + bb;
        }
    }
}

extern "C" void kernel_launch(void* const* d_in, const int* in_sizes, int n_in,
                              void* d_out, int out_size, void* d_ws, size_t ws_size,
                              hipStream_t stream) {
    const float* x  = (const float*)d_in[0];
    const float* wq = (const float*)d_in[1];
    const float* bq = (const float*)d_in[2];
    const float* wk = (const float*)d_in[3];
    const float* bk = (const float*)d_in[4];
    const float* wv = (const float*)d_in[5];
    const float* bv = (const float*)d_in[6];
    const float* wo = (const float*)d_in[7];
    const float* bo = (const float*)d_in[8];
    float* ws = (float*)d_ws;
    float* out = (float*)d_out;

    k_prep<<<8448, 256, 0, stream>>>(x, wq, wk, wv, wo, ws);
    k_qkv_mfma<<<dim3(128, 3, 2), 256, 0, stream>>>(bq, bk, bv, ws);
    k_colstats<<<dim3(16, 16, 8), 256, 0, stream>>>(ws);
    k_afin<<<128, 256, 0, stream>>>(ws);
    k_attnpv<<<dim3(32, 8, 8), 256, 0, stream>>>(ws);
    k_outproj_mfma<<<dim3(128, 4), 256, 0, stream>>>(bo, ws, out);
}

// Round 8
// 204.344 us; speedup vs baseline: 1.1111x; 1.0783x over previous
//
#include <hip/hip_runtime.h>

#define SEQ   4096
#define HH    4
#define SCALE 0.125f
// exp2-folded constants: p = exp2(s*SC2 + a2), SC2 = SCALE*log2(e).
// SC2 folded into Q at projection (wq,bq pre-scaled); a2_j rides in the MFMA
// C-initializer. Softmax normalizes over i (axis=1): stats pass computes
// COLUMN sums Z_j = sum_i exp2(s'_ij + C16).
#define SC2   0.18033688011112042f
#define C16   -23.083120654223414f   /* -16*log2(e) */

typedef __bf16 bf16x8 __attribute__((ext_vector_type(8)));
typedef __bf16 bf16x4 __attribute__((ext_vector_type(4)));
typedef float  f32x4  __attribute__((ext_vector_type(4)));

// ---- ws layout (float offsets) ----
// Q frag-packed: [bh][tile16][frag2][512] (Q pre-scaled by SC2);
// K frag-packed with PERMUTED rows: [bh][jc32][tile2][frag2][512],
//   tile row m <-> j = (m>>2)*8 + t*4 + (m&3) so S^T = mfma(K,Q) lands
//   directly in the PV B-fragment layout (no cross-lane redistribution).
// V: [bh][jc32][nd4][512].
constexpr size_t OFF_W16  = 0;         // 4x65536 bf16 weights (wq slab pre-scaled by SC2)
constexpr size_t OFF_A    = 131072;    // [bh*S+j] a2_j = C16 - log2(Z_j)
constexpr size_t OFF_AO   = 294912;    // [8192][256] fp32 attn out (atomic)
constexpr size_t OFF_X16  = 9732096;   // 6291456 bf16 (x cast)
constexpr size_t OFF_Q16  = 12877824;  // packed Q,K,V bf16 regions
constexpr size_t K16OFF   = 2097152;
constexpr size_t V16OFF   = 4194304;
constexpr size_t OFF_PZ   = 16023552;  // [16][32768] colstats partials

__device__ __forceinline__ f32x4 mf(bf16x8 a, bf16x8 b, f32x4 c) {
    return __builtin_amdgcn_mfma_f32_16x16x32_bf16(a, b, c, 0, 0, 0);
}

__device__ __forceinline__ void gload16(const __bf16* g, __bf16* l) {
    __builtin_amdgcn_global_load_lds(
        (const __attribute__((address_space(1))) unsigned int*)g,
        (__attribute__((address_space(3))) unsigned int*)l, 16, 0, 0);
}

__device__ __forceinline__ float ex2(float x) {
    return __builtin_amdgcn_exp2f(x);
}

// ---- prep: cast x, cast weights (wq pre-scaled by SC2), zero AO ----
__global__ void k_prep(const float* __restrict__ x,
                       const float* __restrict__ wq, const float* __restrict__ wk,
                       const float* __restrict__ wv, const float* __restrict__ wo,
                       float* __restrict__ ws) {
    int bx = blockIdx.x, t = threadIdx.x;
    if (bx < 6144) {
        size_t i4 = ((size_t)bx * 256 + t) * 4;
        float4 v = *(const float4*)(x + i4);
        bf16x4 o = {(__bf16)v.x, (__bf16)v.y, (__bf16)v.z, (__bf16)v.w};
        *(bf16x4*)((__bf16*)(ws + OFF_X16) + i4) = o;
    } else if (bx < 6400) {
        int q = bx - 6144;
        int y = q >> 6;
        const float* src = (y == 0) ? wq : (y == 1) ? wk : (y == 2) ? wv : wo;
        float sc = (y == 0) ? SC2 : 1.0f;
        size_t i4 = ((size_t)(q & 63) * 256 + t) * 4;
        float4 v = *(const float4*)(src + i4);
        bf16x4 o = {(__bf16)(v.x * sc), (__bf16)(v.y * sc),
                    (__bf16)(v.z * sc), (__bf16)(v.w * sc)};
        *(bf16x4*)((__bf16*)(ws + OFF_W16) + (size_t)y * 65536 + i4) = o;
    } else {
        size_t i4 = ((size_t)(bx - 6400) * 256 + t) * 4;
        *(float4*)(ws + OFF_AO + i4) = make_float4(0.f, 0.f, 0.f, 0.f);
    }
}

// ---- QKV projection; grid (128, 3, 2): z splits the 256-col output ----
__global__ __launch_bounds__(256) void k_qkv_mfma(const float* __restrict__ bq,
                                                  const float* __restrict__ bk,
                                                  const float* __restrict__ bv,
                                                  float* __restrict__ ws) {
    int t = threadIdx.x, lane = t & 63, w = t >> 6;
    int yw = blockIdx.y;
    int ntb = blockIdx.z * 8;
    int row0 = blockIdx.x * 64 + w * 16;
    int mrow = lane & 15, quad = lane >> 4;
    const __bf16* X16 = (const __bf16*)(ws + OFF_X16);
    const __bf16* W16 = (const __bf16*)(ws + OFF_W16) + (size_t)yw * 65536;
    const float* bias = (yw == 0) ? bq : (yw == 1) ? bk : bv;
    __bf16* Qb = (__bf16*)(ws + OFF_Q16);
    f32x4 acc[8];
#pragma unroll
    for (int n = 0; n < 8; n++) acc[n] = {0.f, 0.f, 0.f, 0.f};
    const __bf16* ap = X16 + (size_t)(row0 + mrow) * 768 + yw * 256 + quad * 8;
    const __bf16* bp = W16 + (size_t)ntb * 4096 + (size_t)mrow * 256 + quad * 8;
    for (int kc = 0; kc < 256; kc += 32) {
        bf16x8 a = *(const bf16x8*)(ap + kc);
#pragma unroll
        for (int nt = 0; nt < 8; nt++) {
            bf16x8 b = *(const bf16x8*)(bp + (size_t)nt * 4096 + kc);
            acc[nt] = mf(a, b, acc[nt]);
        }
    }
#pragma unroll
    for (int nt = 0; nt < 8; nt++) {
        int n = (ntb + nt) * 16 + mrow;
        float bb = bias[n];
        if (yw == 0) bb *= SC2;
        int h = n >> 6, d = n & 63;
#pragma unroll
        for (int r = 0; r < 4; r++) {
            int sg = row0 + quad * 4 + r;
            int b_ = sg >> 12, s = sg & 4095;
            int bh = b_ * HH + h;
            float val = acc[nt][r] + bb;
            if (yw == 0) {
                int tile = s >> 4, m = s & 15, frag = d >> 5, q2 = (d >> 3) & 3, e = d & 7;
                size_t idx = (((size_t)bh * 256 + tile) * 2 + frag) * 512 +
                             (size_t)(q2 * 16 + m) * 8 + e;
                Qb[idx] = (__bf16)val;
            } else if (yw == 1) {
                int jc = s >> 5, jj = s & 31;
                int tl = (jj >> 2) & 1, m = ((jj >> 3) << 2) | (jj & 3);
                int frag = d >> 5, q2 = (d >> 3) & 3, e = d & 7;
                size_t idx = (((size_t)bh * 128 + jc) * 4 + tl * 2 + frag) * 512 +
                             (size_t)(q2 * 16 + m) * 8 + e;
                Qb[K16OFF + idx] = (__bf16)val;
            } else {
                int jc = s >> 5, qk = (s >> 3) & 3, e = s & 7;
                int nd = d >> 4, nl = d & 15;
                size_t idx = (((size_t)bh * 128 + jc) * 4 + nd) * 512 +
                             (size_t)(qk * 16 + nl) * 8 + e;
                Qb[V16OFF + idx] = (__bf16)val;
            }
        }
    }
}

// ---- pass 1: Z_j partials; 64 j/wave (8 K frags), 256 i/block ----
// grid (16 jb, 16 iy, 8 bh) = 2048 blocks; Q staged 64-i chunks dbuf'd.
__global__ __launch_bounds__(256) void k_colstats(float* __restrict__ ws) {
    __shared__ __bf16 qbuf[2][4096];
    int t = threadIdx.x, lane = t & 63, w = t >> 6;
    int jb = blockIdx.x, iy = blockIdx.y, bh = blockIdx.z;
    int jc0 = jb * 8 + w * 2;          // two 32-j chunks per wave
    const __bf16* Qp = (const __bf16*)(ws + OFF_Q16);
    const __bf16* Kp = Qp + K16OFF;
    const __bf16* kb = Kp + ((size_t)(bh * 128 + jc0) * 4) * 512 + lane * 8;
    bf16x8 kA0 = *(const bf16x8*)(kb);
    bf16x8 kA1 = *(const bf16x8*)(kb + 512);
    bf16x8 kB0 = *(const bf16x8*)(kb + 1024);
    bf16x8 kB1 = *(const bf16x8*)(kb + 1536);
    bf16x8 kC0 = *(const bf16x8*)(kb + 2048);
    bf16x8 kC1 = *(const bf16x8*)(kb + 2560);
    bf16x8 kD0 = *(const bf16x8*)(kb + 3072);
    bf16x8 kD1 = *(const bf16x8*)(kb + 3584);
    const __bf16* q0 = Qp + ((size_t)(bh * 256 + iy * 16) * 2) * 512 +
                       w * 1024 + lane * 8;
    gload16(q0, qbuf[0] + w * 1024);
    gload16(q0 + 512, qbuf[0] + w * 1024 + 512);
    __syncthreads();
    const f32x4 cin = {C16, C16, C16, C16};
    float z0 = 0.f, z1 = 0.f, z2 = 0.f, z3 = 0.f;
    for (int ic = 0; ic < 4; ic++) {
        const __bf16* cur = qbuf[ic & 1];
        if (ic < 3) {
            const __bf16* qn = Qp + ((size_t)(bh * 256 + iy * 16 + (ic + 1) * 4) * 2) * 512 +
                               w * 1024 + lane * 8;
            gload16(qn, qbuf[(ic + 1) & 1] + w * 1024);
            gload16(qn + 512, qbuf[(ic + 1) & 1] + w * 1024 + 512);
        }
#pragma unroll
        for (int it = 0; it < 4; it++) {
            bf16x8 a0 = *(const bf16x8*)(cur + it * 1024 + lane * 8);
            bf16x8 a1 = *(const bf16x8*)(cur + it * 1024 + 512 + lane * 8);
            f32x4 cA = mf(a0, kA0, cin); cA = mf(a1, kA1, cA);
            f32x4 cB = mf(a0, kB0, cin); cB = mf(a1, kB1, cB);
            f32x4 cC = mf(a0, kC0, cin); cC = mf(a1, kC1, cC);
            f32x4 cD = mf(a0, kD0, cin); cD = mf(a1, kD1, cD);
#pragma unroll
            for (int r = 0; r < 4; r++) {
                z0 += ex2(cA[r]);
                z1 += ex2(cB[r]);
                z2 += ex2(cC[r]);
                z3 += ex2(cD[r]);
            }
        }
        __syncthreads();
    }
    z0 += __shfl_xor(z0, 16, 64);
    z0 += __shfl_xor(z0, 32, 64);
    z1 += __shfl_xor(z1, 16, 64);
    z1 += __shfl_xor(z1, 32, 64);
    z2 += __shfl_xor(z2, 16, 64);
    z2 += __shfl_xor(z2, 32, 64);
    z3 += __shfl_xor(z3, 16, 64);
    z3 += __shfl_xor(z3, 32, 64);
    if (lane < 16) {
        // col m of tile t in chunk c -> j = (jc0+c)*32 + (m>>2)*8 + t*4 + (m&3)
        size_t o = OFF_PZ + (size_t)iy * 32768 + (size_t)bh * SEQ +
                   jc0 * 32 + ((lane >> 2) << 3) + (lane & 3);
        ws[o] = z0;
        ws[o + 4] = z1;
        ws[o + 32] = z2;
        ws[o + 36] = z3;
    }
}

// ---- pass 1b: a2_j = C16 - log2(sum of partials) ----
__global__ void k_afin(float* __restrict__ ws) {
    int idx = blockIdx.x * 256 + threadIdx.x;
    const float* pz = ws + OFF_PZ;
    float Z = 0.f;
#pragma unroll
    for (int y = 0; y < 16; y++) Z += pz[(size_t)y * 32768 + idx];
    ws[OFF_A + idx] = C16 - __log2f(Z);
}

// ---- pass 2: 32 i/wave, 1024 j/block (32 jt); 3-buffer K/V pipeline with
// counted vmcnt(2) (never drains to 0 in-loop), raw s_barrier; a2 slab in
// LDS (broadcast ds_reads, keeps vmem FIFO = only the 2 gload_lds/iter).
// grid (32,4,8) = 1024 blocks -> 4/CU. ----
__global__ __launch_bounds__(256) void k_attnpv(float* __restrict__ ws) {
    __shared__ __align__(16) char pool[28672];
    // pool: 3 bufs x (K 4KB + V 4KB) = 24KB, sA 4KB at +24576
    float* sA = (float*)(pool + 24576);      // [1024] a2 for this j-slab
    int t = threadIdx.x, lane = t & 63, w = t >> 6;
    int jy = blockIdx.y, bh = blockIdx.z;    // jy: 1024-j slab
    int itp = blockIdx.x * 4 + w;            // 0..127
    int it0 = itp * 2;                       // two 16-row Q tiles
    int mrow = lane & 15, quad = lane >> 4;
    const __bf16* Qp = (const __bf16*)(ws + OFF_Q16);
    const __bf16* Kp = Qp + K16OFF;
    const __bf16* Vp = Qp + V16OFF;

    // stage a2 slab (1024 floats) into LDS
    {
        const float* Ag = ws + OFF_A + (size_t)bh * SEQ + jy * 1024;
        *(float4*)(sA + t * 4) = *(const float4*)(Ag + t * 4);
    }
    const __bf16* qb = Qp + ((size_t)(bh * 256 + it0) * 2) * 512 + lane * 8;
    bf16x8 aq00 = *(const bf16x8*)(qb);
    bf16x8 aq01 = *(const bf16x8*)(qb + 512);
    bf16x8 aq10 = *(const bf16x8*)(qb + 1024);
    bf16x8 aq11 = *(const bf16x8*)(qb + 1536);

    f32x4 oT0[4], oT1[4];
#pragma unroll
    for (int nd = 0; nd < 4; nd++) {
        oT0[nd] = {0.f, 0.f, 0.f, 0.f};
        oT1[nd] = {0.f, 0.f, 0.f, 0.f};
    }
    int c0g = jy * 32;                       // first 32-j chunk of this slab
    const __bf16* kg = Kp + ((size_t)(bh * 128 + c0g) * 4) * 512 + w * 512 + lane * 8;
    const __bf16* vg = Vp + ((size_t)(bh * 128 + c0g) * 4) * 512 + w * 512 + lane * 8;
    // stage jt=0 into buffer 0
    gload16(kg, (__bf16*)pool + w * 512);
    gload16(vg, (__bf16*)(pool + 4096) + w * 512);
    kg += 2048; vg += 2048;
    __syncthreads();   // full drain once (Q regs, sA, buf0)

    int bc = 0;  // buffer holding jt
    for (int jt = 0; jt < 32; ++jt) {
        int bn = (bc == 2) ? 0 : bc + 1;
        if (jt < 31) {
            // issue jt+1 into buf bn; jt's loads stay ahead in the FIFO
            gload16(kg, (__bf16*)(pool + bn * 8192) + w * 512);
            gload16(vg, (__bf16*)(pool + bn * 8192 + 4096) + w * 512);
            kg += 2048; vg += 2048;
            asm volatile("s_waitcnt vmcnt(2)" ::: "memory");
        } else {
            asm volatile("s_waitcnt vmcnt(0)" ::: "memory");
        }
        __builtin_amdgcn_s_barrier();
        const __bf16* curK = (const __bf16*)(pool + bc * 8192);
        const __bf16* curV = (const __bf16*)(pool + bc * 8192 + 4096);
        f32x4 aL = *(const f32x4*)(sA + jt * 32 + quad * 8);
        f32x4 aH = *(const f32x4*)(sA + jt * 32 + quad * 8 + 4);
        bf16x8 ck0 = *(const bf16x8*)(curK + lane * 8);
        bf16x8 ck1 = *(const bf16x8*)(curK + 512 + lane * 8);
        bf16x8 ck2 = *(const bf16x8*)(curK + 1024 + lane * 8);
        bf16x8 ck3 = *(const bf16x8*)(curK + 1536 + lane * 8);
        // S^T with bias folded into C-init: c = s*SC2 + a2  (Q pre-scaled)
        f32x4 c00 = mf(ck0, aq00, aL); c00 = mf(ck1, aq01, c00);
        f32x4 c01 = mf(ck2, aq00, aH); c01 = mf(ck3, aq01, c01);
        f32x4 c10 = mf(ck0, aq10, aL); c10 = mf(ck1, aq11, c10);
        f32x4 c11 = mf(ck2, aq10, aH); c11 = mf(ck3, aq11, c11);
        bf16x8 pb0, pb1;
#pragma unroll
        for (int r = 0; r < 4; r++) {
            pb0[r]     = (__bf16)ex2(c00[r]);
            pb0[4 + r] = (__bf16)ex2(c01[r]);
            pb1[r]     = (__bf16)ex2(c10[r]);
            pb1[4 + r] = (__bf16)ex2(c11[r]);
        }
#pragma unroll
        for (int nd = 0; nd < 4; nd++) {
            bf16x8 bv = *(const bf16x8*)(curV + nd * 512 + lane * 8);
            oT0[nd] = mf(bv, pb0, oT0[nd]);
            oT1[nd] = mf(bv, pb1, oT1[nd]);
        }
        bc = bn;
    }
    __syncthreads();   // protect LDS reuse below from slow waves

    // epilogue: wave-local LDS transpose (pool is dead), coalesced atomics
    float* sO = (float*)pool + (size_t)w * 1040;   // 16 x 65 floats per wave
    int b = bh >> 2, h = bh & 3;
    float* AO = ws + OFF_AO;
    int i0 = it0 * 16;
#pragma unroll
    for (int nd = 0; nd < 4; nd++)
#pragma unroll
        for (int r = 0; r < 4; r++)
            sO[mrow * 65 + nd * 16 + quad * 4 + r] = oT0[nd][r];
#pragma unroll
    for (int c = 0; c < 16; c++)
        atomicAdd(&AO[((size_t)(b * SEQ + i0 + c)) * 256 + h * 64 + lane],
                  sO[c * 65 + lane]);
#pragma unroll
    for (int nd = 0; nd < 4; nd++)
#pragma unroll
        for (int r = 0; r < 4; r++)
            sO[mrow * 65 + nd * 16 + quad * 4 + r] = oT1[nd][r];
#pragma unroll
    for (int c = 0; c < 16; c++)
        atomicAdd(&AO[((size_t)(b * SEQ + i0 + 16 + c)) * 256 + h * 64 + lane],
                  sO[c * 65 + lane]);
}

// ---- output projection; grid (128, 4): y splits cols -> 512 blocks ----
__global__ __launch_bounds__(256) void k_outproj_mfma(const float* __restrict__ bo,
                                                      float* __restrict__ ws,
                                                      float* __restrict__ out) {
    int t = threadIdx.x, lane = t & 63, w = t >> 6;
    int row0 = blockIdx.x * 64 + w * 16;
    int ntb = blockIdx.y * 4;
    int mrow = lane & 15, quad = lane >> 4;
    const float* AO = ws + OFF_AO;
    const __bf16* W16 = (const __bf16*)(ws + OFF_W16) + (size_t)3 * 65536;
    f32x4 acc[4];
#pragma unroll
    for (int n = 0; n < 4; n++) acc[n] = {0.f, 0.f, 0.f, 0.f};
    const float* ap = AO + (size_t)(row0 + mrow) * 256 + quad * 8;
    const __bf16* bp = W16 + (size_t)ntb * 4096 + (size_t)mrow * 256 + quad * 8;
    for (int kc = 0; kc < 256; kc += 32) {
        float4 u = *(const float4*)(ap + kc);
        float4 v = *(const float4*)(ap + kc + 4);
        bf16x8 a = {(__bf16)u.x, (__bf16)u.y, (__bf16)u.z, (__bf16)u.w,
                    (__bf16)v.x, (__bf16)v.y, (__bf16)v.z, (__bf16)v.w};
#pragma unroll
        for (int nt = 0; nt < 4; nt++) {
            bf16x8 b = *(const bf16x8*)(bp + (size_t)nt * 4096 + kc);
            acc[nt] = mf(a, b, acc[nt]);
        }
    }
#pragma unroll
    for (int nt = 0; nt < 4; nt++) {
        int n = (ntb + nt) * 16 + mrow;
        float bb = bo[n];
#pragma unroll
        for (int r = 0; r < 4; r++) {
            int sg = row0 + quad * 4 + r;
            out[(size_t)sg * 256 + n] = acc[nt][r] + bb;
        }
    }
}

extern "C" void kernel_launch(void* const* d_in, const int* in_sizes, int n_in,
                              void* d_out, int out_size, void* d_ws, size_t ws_size,
                              hipStream_t stream) {
    const float* x  = (const float*)d_in[0];
    const float* wq = (const float*)d_in[1];
    const float* bq = (const float*)d_in[2];
    const float* wk = (const float*)d_in[3];
    const float* bk = (const float*)d_in[4];
    const float* wv = (const float*)d_in[5];
    const float* bv = (const float*)d_in[6];
    const float* wo = (const float*)d_in[7];
    const float* bo = (const float*)d_in[8];
    float* ws = (float*)d_ws;
    float* out = (float*)d_out;

    k_prep<<<8448, 256, 0, stream>>>(x, wq, wk, wv, wo, ws);
    k_qkv_mfma<<<dim3(128, 3, 2), 256, 0, stream>>>(bq, bk, bv, ws);
    k_colstats<<<dim3(16, 16, 8), 256, 0, stream>>>(ws);
    k_afin<<<128, 256, 0, stream>>>(ws);
    k_attnpv<<<dim3(32, 4, 8), 256, 0, stream>>>(ws);
    k_outproj_mfma<<<dim3(128, 4), 256, 0, stream>>>(bo, ws, out);
}